// Round 16
// baseline (1223.918 us; speedup 1.0000x reference)
//
#include <hip/hip_runtime.h>
#include <hip/hip_bf16.h>
#include <stdint.h>

typedef unsigned short u16;
typedef unsigned int u32;
typedef __attribute__((ext_vector_type(8))) short i16x8;   // 8 bf16 payload
typedef __attribute__((ext_vector_type(4))) float f32x4;

#define DEV __device__ __forceinline__

constexpr int T = 1024, D = 256, H = 4, NH = 8192, NF = 32768, HALF = 4096;

// ---------------- workspace layout (bytes); total ~252 MB ----------------
constexpr size_t OFF_DXT  = 0;                                  // (H,NH,D) bf16 [P-perm rows]
constexpr size_t OFF_DYT  = OFF_DXT  + (size_t)H*NH*D*2;        // (H,NH,D) bf16 [P-perm rows]
constexpr size_t OFF_ENCT = OFF_DYT  + (size_t)H*NH*D*2;        // (D,NF)   bf16 [P-perm cols]
constexpr size_t OFF_ROT  = OFF_ENCT + (size_t)D*NF*2;          // (D,D)    bf16
constexpr size_t OFF_COS  = OFF_ROT  + (size_t)D*D*2;           // (T,HALF) f32
constexpr size_t OFF_SIN  = OFF_COS  + (size_t)T*HALF*4;        // (T,HALF) f32
constexpr size_t OFF_V    = OFF_SIN  + (size_t)T*HALF*4;        // (T,D)    f32
constexpr size_t OFF_VBF  = OFF_V    + (size_t)T*D*4;           // (T,D)    bf16
constexpr size_t OFF_VT   = OFF_VBF  + (size_t)T*D*2;           // (D,T)    bf16
constexpr size_t OFF_X    = OFF_VT   + (size_t)T*D*2;           // (T,NF)   bf16 [perm]
constexpr size_t OFF_XR   = OFF_X    + (size_t)T*NF*2;          // (T,NF)   bf16 [perm] (reused as y)
constexpr size_t OFF_SC   = OFF_XR   + (size_t)T*NF*2;          // (H,T,T)  bf16
constexpr size_t OFF_LA   = OFF_SC   + (size_t)H*T*T*2;         // (H,T,D)  bf16
constexpr size_t OFF_PART = OFF_LA   + (size_t)H*T*D*2;         // 32MB: scb (16,T,T) bf16 overlays part (16,T,D) f32
constexpr size_t WS_NEED  = OFF_PART + (size_t)8*T*T*4;

// Feature permutation (within each head's 8192 cols): orig j<4096 -> 2j,
// orig j>=4096 -> 2(j-4096)+1. Pairs (j, j+4096) land adjacent -> rope is local
// to any 16B fragment. Applied to dxT/dyT (out rows) + encT (in rows) at
// prepass; sc/enc are feature-inner-products and y*x is elementwise, so all
// downstream math is permutation-invariant.

DEV u16 f2bf(float f) {            // round-to-nearest-even f32 -> bf16
  u32 u = __float_as_uint(f);
  u += 0x7FFFu + ((u >> 16) & 1u);
  return (u16)(u >> 16);
}
DEV float bf2f(u16 u) { return __uint_as_float(((u32)u) << 16); }

DEV float2 block_sum2(float a, float b, float* sb) {   // 256-thread block, 4 waves
  #pragma unroll
  for (int o = 32; o > 0; o >>= 1) {
    a += __shfl_down(a, o, 64);
    b += __shfl_down(b, o, 64);
  }
  const int w = threadIdx.x >> 6;
  __syncthreads();
  if ((threadIdx.x & 63) == 0) { sb[w*2] = a; sb[w*2+1] = b; }
  __syncthreads();
  return make_float2(sb[0]+sb[2]+sb[4]+sb[6], sb[1]+sb[3]+sb[5]+sb[7]);
}

// ======== 128x128-tile gemm_bt core: C = A(128xK) * B(128xK)^T, bf16->f32 ========
// LDS tile: 128 rows x 64 bf16 (128B/row). XOR swizzle: phys_byte = row*128 +
// (logical_byte ^ ((row&7)<<4)). global_load_lds writes linearly -> pre-swizzle the
// GLOBAL source segment, swizzle again on ds_read (guide rule 21 / T2).
DEV void stage128(const u16* __restrict__ g, int ld, char* lds, int wave, int lane) {
  #pragma unroll
  for (int i = 0; i < 4; ++i) {
    const int f = (wave*4 + i)*64 + lane;       // 0..1023 16B-chunks
    const int row = f >> 3, seg = f & 7;
    const int segl = seg ^ (row & 7);
    const u16* src = g + (size_t)row*ld + segl*8;
    __builtin_amdgcn_global_load_lds(
        (const __attribute__((address_space(1))) void*)src,
        (__attribute__((address_space(3))) void*)(lds + ((wave*4 + i) << 10)),
        16, 0, 0);
  }
}

// 64-row variant (8KB): same 128B-row proven swizzle, 512 chunks, 2/thread
DEV void stageB64(const u16* __restrict__ g, int ld, char* lds, int tid) {
  #pragma unroll
  for (int i = 0; i < 2; ++i) {
    const int f = i*256 + tid;                  // 0..511 16B-chunks
    const int row = f >> 3, seg = f & 7;
    const int segl = seg ^ (row & 7);
    const u16* src = g + (size_t)row*ld + segl*8;
    __builtin_amdgcn_global_load_lds(
        (const __attribute__((address_space(1))) void*)src,
        (__attribute__((address_space(3))) void*)(lds + ((size_t)f << 4)),
        16, 0, 0);
  }
}

// MFMA body for one staged K-tile pair (BK=64 cores)
DEV void mfma_tile(const char* Ac, const char* Bc, int wm, int wn, int lr, int lk,
                   f32x4 acc[4][4]) {
  #pragma unroll
  for (int kk = 0; kk < 2; ++kk) {
    const int lcol = kk*64 + lk*16;
    i16x8 af[4], bfv[4];
    #pragma unroll
    for (int m = 0; m < 4; ++m) {
      const int row = wm*64 + m*16 + lr;
      af[m] = *(const i16x8*)(Ac + row*128 + (lcol ^ ((row & 7) << 4)));
    }
    #pragma unroll
    for (int n = 0; n < 4; ++n) {
      const int row = wn*64 + n*16 + lr;
      bfv[n] = *(const i16x8*)(Bc + row*128 + (lcol ^ ((row & 7) << 4)));
    }
    #pragma unroll
    for (int m = 0; m < 4; ++m)
      #pragma unroll
      for (int n = 0; n < 4; ++n)
        acc[m][n] = __builtin_amdgcn_mfma_f32_16x16x32_bf16(af[m], bfv[n], acc[m][n], 0, 0, 0);
  }
}

// 128x64 output variant: B tile 64 rows, acc[4][2]; same swizzle, BK=64
DEV void mfma_tile_n2(const char* Ac, const char* Bc, int wm, int wn, int lr, int lk,
                      f32x4 acc[4][2]) {
  #pragma unroll
  for (int kk = 0; kk < 2; ++kk) {
    const int lcol = kk*64 + lk*16;
    i16x8 af[4], bfv[2];
    #pragma unroll
    for (int m = 0; m < 4; ++m) {
      const int row = wm*64 + m*16 + lr;
      af[m] = *(const i16x8*)(Ac + row*128 + (lcol ^ ((row & 7) << 4)));
    }
    #pragma unroll
    for (int n = 0; n < 2; ++n) {
      const int row = wn*32 + n*16 + lr;        // 0..63
      bfv[n] = *(const i16x8*)(Bc + row*128 + (lcol ^ ((row & 7) << 4)));
    }
    #pragma unroll
    for (int m = 0; m < 4; ++m)
      #pragma unroll
      for (int n = 0; n < 2; ++n)
        acc[m][n] = __builtin_amdgcn_mfma_f32_16x16x32_bf16(af[m], bfv[n], acc[m][n], 0, 0, 0);
  }
}

// Double-buffered core (64KB LDS): for the remaining grid-limited kernel (out).
// sb-core rule (round-9 lesson): ONLY profitable when grid >> 2x CU count.
// Round-11/13 lesson: keep nkt >= 4 and 128B LDS rows (the proven swizzle).
DEV void gemm_bt_core(const u16* __restrict__ Ab, int lda,
                      const u16* __restrict__ Bb, int ldb,
                      int nkt, char* smem, f32x4 acc[4][4]) {
  const int tid = threadIdx.x, lane = tid & 63, wave = tid >> 6;
  const int wm = wave >> 1, wn = wave & 1;
  const int lr = lane & 15, lk = lane >> 4;
  char* As = smem;              // 2 x 16KB
  char* Bs = smem + 32768;      // 2 x 16KB
  #pragma unroll
  for (int m = 0; m < 4; ++m)
    #pragma unroll
    for (int n = 0; n < 4; ++n) acc[m][n] = f32x4{0.f, 0.f, 0.f, 0.f};
  stage128(Ab, lda, As, wave, lane);
  stage128(Bb, ldb, Bs, wave, lane);
  __syncthreads();
  for (int kt = 0; kt < nkt; ++kt) {
    const int cur = kt & 1;
    if (kt + 1 < nkt) {           // prefetch next K-tile into other buffer
      stage128(Ab + (size_t)(kt+1)*64, lda, As + ((cur^1) << 14), wave, lane);
      stage128(Bb + (size_t)(kt+1)*64, ldb, Bs + ((cur^1) << 14), wave, lane);
    }
    mfma_tile(As + (cur << 14), Bs + (cur << 14), wm, wn, lr, lk, acc);
    __syncthreads();              // drains vmcnt(0): staged tile visible next iter
  }
}

// 48KB db core: A 128xK (2x16KB), B 64xK (2x8KB) -> 3 blocks/CU.
// Round-15-PROVEN on sc (62.5->56.8us, conflicts flat, occupancy 12.5->22%):
// same swizzle/BK as the 64KB core, B-tile halved -> +50% co-resident waves
// to overlap the stage->barrier chain. Round-16: applied to enc + av too.
DEV void gemm_bt_core_n2(const u16* __restrict__ Ab, int lda,
                         const u16* __restrict__ Bb, int ldb,
                         int nkt, char* smem, f32x4 acc[4][2]) {
  const int tid = threadIdx.x, lane = tid & 63, wave = tid >> 6;
  const int wm = wave >> 1, wn = wave & 1;
  const int lr = lane & 15, lk = lane >> 4;
  char* As = smem;              // 2 x 16KB
  char* Bs = smem + 32768;      // 2 x 8KB
  #pragma unroll
  for (int m = 0; m < 4; ++m)
    #pragma unroll
    for (int n = 0; n < 2; ++n) acc[m][n] = f32x4{0.f, 0.f, 0.f, 0.f};
  stage128(Ab, lda, As, wave, lane);
  stageB64(Bb, ldb, Bs, tid);
  __syncthreads();
  for (int kt = 0; kt < nkt; ++kt) {
    const int cur = kt & 1;
    if (kt + 1 < nkt) {
      stage128(Ab + (size_t)(kt+1)*64, lda, As + ((cur^1) << 14), wave, lane);
      stageB64(Bb + (size_t)(kt+1)*64, ldb, Bs + ((cur^1) << 13), tid);
    }
    mfma_tile_n2(As + (cur << 14), Bs + (cur << 13), wm, wn, lr, lk, acc);
    __syncthreads();
  }
}

// Single-buffered core (32KB LDS): ONLY for huge-grid kernels (x_rope: 2048
// blocks, y: 2048 blocks). Stage latency exposed per iteration, but ~5
// blocks/CU of cross-block TLP covers it (verified round 8: x_rope 72->61us).
// NO min-waves launch bound (round-7: (256,5) capped VGPR at 48 -> spills).
DEV void gemm_bt_core_sb(const u16* __restrict__ Ab, int lda,
                         const u16* __restrict__ Bb, int ldb,
                         int nkt, char* smem, f32x4 acc[4][4]) {
  const int tid = threadIdx.x, lane = tid & 63, wave = tid >> 6;
  const int wm = wave >> 1, wn = wave & 1;
  const int lr = lane & 15, lk = lane >> 4;
  char* As = smem;              // 16KB
  char* Bs = smem + 16384;      // 16KB
  #pragma unroll
  for (int m = 0; m < 4; ++m)
    #pragma unroll
    for (int n = 0; n < 4; ++n) acc[m][n] = f32x4{0.f, 0.f, 0.f, 0.f};
  for (int kt = 0; kt < nkt; ++kt) {
    stage128(Ab + (size_t)kt*64, lda, As, wave, lane);
    stage128(Bb + (size_t)kt*64, ldb, Bs, wave, lane);
    __syncthreads();
    mfma_tile(As, Bs, wm, wn, lr, lk, acc);
    __syncthreads();
  }
}

// C/D frag map (m89-verified): col = lane&15, row = (lane>>4)*4 + reg
#define EPILOG_IDX() \
  const int lane = threadIdx.x & 63, wave = threadIdx.x >> 6; \
  const int wm = wave >> 1, wn = wave & 1, lr = lane & 15, lk = lane >> 4; \
  const int r0 = wm*64 + lk*4; \
  const int c0 = wn*64 + lr;

constexpr int TS = 136;   // LDS row stride (u16): 272B, 16B-aligned, bank-spread

// ---- 128x64 coalesced store via LDS [128][72] (18.4KB, fits 48KB smem) ----
// (numerically verified in rounds 11/15)
DEV void store_tile64(const f32x4 acc[4][2], u16* __restrict__ dst, int ld, char* smem) {
  u16* tb = (u16*)smem;
  const int lane = threadIdx.x & 63, wave = threadIdx.x >> 6;
  const int wm = wave >> 1, wn = wave & 1, lr = lane & 15, lk = lane >> 4;
  const int r0 = wm*64 + lk*4, c0 = wn*32 + lr;
  #pragma unroll
  for (int m = 0; m < 4; ++m)
    #pragma unroll
    for (int n = 0; n < 2; ++n)
      #pragma unroll
      for (int r = 0; r < 4; ++r)
        tb[(size_t)(r0 + m*16 + r)*72 + c0 + n*16] = f2bf(acc[m][n][r]);
  __syncthreads();
  const int rr = threadIdx.x >> 3;         // 0..31
  const int cc = (threadIdx.x & 7)*8;      // 0..56 (u16 units)
  #pragma unroll
  for (int it = 0; it < 4; ++it) {
    const int row = it*32 + rr;
    *(i16x8*)(dst + (size_t)row*ld + cc) = *(const i16x8*)(tb + (size_t)row*72 + cc);
  }
}

// ---- half-tile coalesced store (64 rows/pass, 17.4KB LDS; fits 32KB smem) ----
// Rows 0-63 live in waves 0-1 (wm=0), rows 64-127 in waves 2-3 (wm=1).
template<int MODE>
DEV void store_tile_sb(const f32x4 acc[4][4], u16* __restrict__ dst, int ld,
                       const u16* __restrict__ xg, char* smem) {
  u16* tb = (u16*)smem;                    // 64 x TS u16 = 17.4KB
  const int lane = threadIdx.x & 63, wave = threadIdx.x >> 6;
  const int wm = wave >> 1, wn = wave & 1, lr = lane & 15, lk = lane >> 4;
  const int c0 = wn*64 + lr, rb = lk*4;
  const int rr = threadIdx.x >> 4, cc = (threadIdx.x & 15)*8;
  #pragma unroll
  for (int half = 0; half < 2; ++half) {
    if (wm == half) {
      #pragma unroll
      for (int m = 0; m < 4; ++m)
        #pragma unroll
        for (int n = 0; n < 4; ++n)
          #pragma unroll
          for (int r = 0; r < 4; ++r) {
            float v = acc[m][n][r];
            if (MODE >= 1) v = fmaxf(v, 0.f);
            tb[(size_t)(rb + m*16 + r)*TS + c0 + n*16] = f2bf(v);
          }
    }
    __syncthreads();
    #pragma unroll
    for (int it = 0; it < 4; ++it) {
      const int row = it*16 + rr;            // 0..63
      const int grow = half*64 + row;
      i16x8 w = *(const i16x8*)(tb + (size_t)row*TS + cc);
      if (MODE == 2) {
        const i16x8 xv = *(const i16x8*)(xg + (size_t)grow*ld + cc);
        #pragma unroll
        for (int j = 0; j < 8; ++j)
          w[j] = (short)f2bf(bf2f((u16)w[j]) * bf2f((u16)xv[j]));
      }
      *(i16x8*)(dst + (size_t)grow*ld + cc) = w;
    }
    __syncthreads();
  }
}

// ---------------- pre-pass kernels ----------------
// PERM 0: plain transpose+cvt.
// PERM 1: apply rope-pair perm to OUTPUT row index (within-head 8192): dxT/dyT.
// PERM 2: apply inverse perm to INPUT row index (global NF, per-head): encT.
template<int PERM>
__global__ __launch_bounds__(256) void k_transpose_cvt(const float* __restrict__ in,
                                                       u16* __restrict__ out, int R, int C) {
  __shared__ float tile[32][33];
  const size_t zoff = (size_t)blockIdx.z * R * C;
  const float* inz = in + zoff;
  u16* outz = out + zoff;
  const int c0 = blockIdx.x << 5, rr0 = blockIdx.y << 5;
  const int tx = threadIdx.x & 31, ty = threadIdx.x >> 5;
  #pragma unroll
  for (int i = 0; i < 4; ++i) {
    int irow = rr0 + ty + i*8;
    if (PERM == 2) {               // new col f holds orig feature Pinv(f)
      const int hh = irow >> 13, j = irow & 8191;
      irow = hh*8192 + ((j & 1) ? (j >> 1) + 4096 : (j >> 1));
    }
    tile[ty + i*8][tx] = inz[(size_t)irow*C + c0 + tx];
  }
  __syncthreads();
  #pragma unroll
  for (int i = 0; i < 4; ++i) {
    const int rr = ty + i*8;
    int orow = c0 + rr;
    if (PERM == 1) {               // orig feature j lands at slot P(j)
      const int j = orow & 8191;
      orow = (orow & ~8191) | ((j < 4096) ? 2*j : 2*(j - 4096) + 1);
    }
    outz[(size_t)orow*R + rr0 + tx] = f2bf(tile[tx][rr]);
  }
}

// tables in (T, HALF) layout: cosT[t*HALF + p], p = pair index
__global__ __launch_bounds__(256) void k_rope_table(float* __restrict__ cosT,
                                                    float* __restrict__ sinT) {
  const int i = blockIdx.x*256 + threadIdx.x;    // 0..4095
  const int t = blockIdx.y;
  const float p = (float)i * (1.f/4096.f);
  const float ang = (float)t * expf(-9.210340371976184f * p);  // 10000^(-i/half)
  cosT[(size_t)t*HALF + i] = cosf(ang);
  sinT[(size_t)t*HALF + i] = sinf(ang);
}

__global__ __launch_bounds__(256) void k_embed(const int* __restrict__ idx,
                                               const float* __restrict__ wte,
                                               float* __restrict__ v,
                                               u16* __restrict__ vbf, u16* __restrict__ vT) {
  __shared__ float sb[8];
  const int t = blockIdx.x, d = threadIdx.x;
  const float val = wte[(size_t)idx[t]*D + d];
  float2 ss = block_sum2(val, val*val, sb);
  const float m = ss.x*(1.f/256.f), var = ss.y*(1.f/256.f) - m*m;
  const float vn = (val - m) * rsqrtf(var + 1e-5f);
  v[(size_t)t*D + d] = vn;
  const u16 b = f2bf(vn);
  vbf[(size_t)t*D + d] = b;
  vT[(size_t)d*T + t] = b;
}

// ---------------- per-layer kernels ----------------
// x = relu(v @ decoder_x) AND xr = rope(x), fused via the pair permutation.
// 1-D grid 2048, XCD-affine decode: the rope-table slice for (nt,mt) is
// h-INDEPENDENT, so the 4 h-variants are placed on the SAME XCD (p%8) within
// 32 dispatch slots -> table fetched once per XCD, not 4x. Per-XCD unique set
// ~ 4MB tables + 2MB dxT + 0.5MB vbf: L2-resident. (round 9: ~-8us/dispatch)
__global__ __launch_bounds__(256) void k_gemm_x_rope(const u16* __restrict__ vbf,
                                                     const u16* __restrict__ dxT,
                                                     u16* __restrict__ x,
                                                     u16* __restrict__ xr,
                                                     const float* __restrict__ cosT,
                                                     const float* __restrict__ sinT) {
  __shared__ char smem[32768];
  const int p = blockIdx.x;
  const int slot = p & 7;
  const int h = (p >> 3) & 3;
  const int seq = p >> 5;                   // 0..63
  const int nt = slot*8 + (seq & 7);        // 0..63
  const int mt = seq >> 3;                  // 0..7
  f32x4 acc[4][4];
  gemm_bt_core_sb(vbf + (size_t)mt*128*D, D,
                  dxT + ((size_t)h*NH + (size_t)nt*128)*D, D, 4, smem, acc);
  u16* tb = (u16*)smem;
  const int lane = threadIdx.x & 63, wave = threadIdx.x >> 6;
  const int wm = wave >> 1, wn = wave & 1, lr = lane & 15, lk = lane >> 4;
  const int c0 = wn*64 + lr, rb = lk*4;
  const int rr = threadIdx.x >> 4, cc = (threadIdx.x & 15)*8;
  const size_t obase = (size_t)mt*128*NF + (size_t)h*NH + (size_t)nt*128;
  const int pbase = (nt*128 + cc) >> 1;    // pair index in [0,4096), mult of 4
  #pragma unroll
  for (int half = 0; half < 2; ++half) {
    if (wm == half) {
      #pragma unroll
      for (int m = 0; m < 4; ++m)
        #pragma unroll
        for (int n = 0; n < 4; ++n)
          #pragma unroll
          for (int r = 0; r < 4; ++r)
            tb[(size_t)(rb + m*16 + r)*TS + c0 + n*16] = f2bf(fmaxf(acc[m][n][r], 0.f));
    }
    __syncthreads();
    #pragma unroll
    for (int it = 0; it < 4; ++it) {
      const int row = it*16 + rr;            // 0..63
      const int grow = half*64 + row;
      const i16x8 w = *(const i16x8*)(tb + (size_t)row*TS + cc);
      *(i16x8*)(x + obase + (size_t)grow*NF + cc) = w;
      const int t = mt*128 + grow;
      const float4 cv = *(const float4*)(cosT + (size_t)t*HALF + pbase);
      const float4 sv = *(const float4*)(sinT + (size_t)t*HALF + pbase);
      i16x8 rg;
      float x1, x2;
      x1 = bf2f((u16)w[0]); x2 = bf2f((u16)w[1]);
      rg[0] = (short)f2bf(x1*cv.x - x2*sv.x); rg[1] = (short)f2bf(x2*cv.x + x1*sv.x);
      x1 = bf2f((u16)w[2]); x2 = bf2f((u16)w[3]);
      rg[2] = (short)f2bf(x1*cv.y - x2*sv.y); rg[3] = (short)f2bf(x2*cv.y + x1*sv.y);
      x1 = bf2f((u16)w[4]); x2 = bf2f((u16)w[5]);
      rg[4] = (short)f2bf(x1*cv.z - x2*sv.z); rg[5] = (short)f2bf(x2*cv.z + x1*sv.z);
      x1 = bf2f((u16)w[6]); x2 = bf2f((u16)w[7]);
      rg[6] = (short)f2bf(x1*cv.w - x2*sv.w); rg[7] = (short)f2bf(x2*cv.w + x1*sv.w);
      *(i16x8*)(xr + obase + (size_t)grow*NF + cc) = rg;
    }
    __syncthreads();
  }
}

// scores partial = xr_h @ xr_h^T over K-chunk (split-K 4 -> K=2048/block),
// LOWER-TRIANGLE TILES ONLY. Round-15 proven: 128x64 tiles via 48KB n2 core
// (BK=64, nkt=32) -> 3 blocks/CU; 56.8us, occupancy 22%, conflicts flat.
// Grid 1152 = 36 tiles x 2 N-halves x 16 slices.
// XCD-affine: slice = p&15 -> XCD p%8 serves slices {z, z+8}.
__global__ __launch_bounds__(256) void k_gemm_sc(const u16* __restrict__ xr,
                                                 u16* __restrict__ scb) {
  __shared__ char smem[49152];
  const int z = blockIdx.x & 15;            // slice = h*4 + kc
  const int j = blockIdx.x >> 4;            // 0..71
  const int i = j >> 1;                     // 0..35 lower-triangle tile id
  const int nh = j & 1;                     // N-half of the 128x128 tile
  int tt = 0;
  while ((tt + 1)*(tt + 2)/2 <= i) ++tt;
  const int st = i - tt*(tt + 1)/2;         // st <= tt (strict-mask survivors)
  const int h = z >> 2, kc = z & 3;
  const u16* base = xr + (size_t)h*NH + (size_t)kc*2048;
  f32x4 acc[4][2];
  gemm_bt_core_n2(base + (size_t)tt*128*NF, NF,
                  base + ((size_t)st*128 + (size_t)nh*64)*NF, NF, 32, smem, acc);
  store_tile64(acc, scb + (size_t)z*T*T + (size_t)tt*128*T + (size_t)st*128 + (size_t)nh*64,
               T, smem);
}

// combine 4 K-chunks + strict-causal mask -> bf16 scores : grid H*T
__global__ __launch_bounds__(256) void k_sc_combine(const u16* __restrict__ scb,
                                                    u16* __restrict__ sc) {
  const int row = blockIdx.x;               // h*T + t
  const int h = row >> 10, t = row & 1023;
  const u16* p0 = scb + ((size_t)(h*4 + 0)*T + t)*T;
  u16* o = sc + (size_t)row*T;
  const int s0 = threadIdx.x*4;
  ushort4 r;
  if (s0 >= t) {
    r.x = 0; r.y = 0; r.z = 0; r.w = 0;
  } else {
    const ushort4 a0 = *(const ushort4*)(p0 + s0);
    const ushort4 a1 = *(const ushort4*)(p0 + T*T + s0);
    const ushort4 a2 = *(const ushort4*)(p0 + 2*(size_t)T*T + s0);
    const ushort4 a3 = *(const ushort4*)(p0 + 3*(size_t)T*T + s0);
    const float vx = bf2f(a0.x) + bf2f(a1.x) + bf2f(a2.x) + bf2f(a3.x);
    const float vy = bf2f(a0.y) + bf2f(a1.y) + bf2f(a2.y) + bf2f(a3.y);
    const float vz = bf2f(a0.z) + bf2f(a1.z) + bf2f(a2.z) + bf2f(a3.z);
    const float vw = bf2f(a0.w) + bf2f(a1.w) + bf2f(a2.w) + bf2f(a3.w);
    r.x = f2bf((s0 + 0 < t) ? vx : 0.f);
    r.y = f2bf((s0 + 1 < t) ? vy : 0.f);
    r.z = f2bf((s0 + 2 < t) ? vz : 0.f);
    r.w = f2bf((s0 + 3 < t) ? vw : 0.f);
  }
  *(ushort4*)(o + s0) = r;
}

// a-partial = scores @ v (split-K 4, K=256/block, nkt=4), VALID (mt,kc) PAIRS
// ONLY: kc <= mt/2 -> 20 of 32 pairs. Round-16: n2 core (48KB, proven r15)
// with 64-wide vT tiles -> grid 320 (was 160 with 96 CUs idle), all
// co-resident. XCD-affine: slot = p&15 -> (h,nt); XCD p%8 serves 2 slots.
__global__ __launch_bounds__(256) void k_gemm_av(const u16* __restrict__ sc,
                                                 const u16* __restrict__ vT,
                                                 float* __restrict__ part) {
  __shared__ char smem[49152];
  const int slot = blockIdx.x & 15;
  const int h = slot >> 2, nt = slot & 3;   // nt: 64-col quarter of D
  int mt = 0, kc = 0, rem = blockIdx.x >> 4;  // 0..19 -> (mt, kc), kc <= mt/2
  #pragma unroll
  for (int m = 0; m < 8; ++m) {
    const int c = (m >> 1) + 1;
    if (rem < c) { mt = m; kc = rem; break; }
    rem -= c;
  }
  f32x4 acc[4][2];
  gemm_bt_core_n2(sc + ((size_t)h*T + (size_t)mt*128)*T + (size_t)kc*256, T,
                  vT + (size_t)nt*64*T + (size_t)kc*256, T, 4, smem, acc);
  const int lane = threadIdx.x & 63, wave = threadIdx.x >> 6;
  const int wm = wave >> 1, wn = wave & 1, lr = lane & 15, lk = lane >> 4;
  const int r0 = wm*64 + lk*4, c0 = wn*32 + lr;
  float* Cp = part + (size_t)(h*4 + kc) * T * D;
  const int tb = mt*128 + r0, cb = nt*64 + c0;
  #pragma unroll
  for (int m = 0; m < 4; ++m)
    #pragma unroll
    for (int n = 0; n < 2; ++n)
      #pragma unroll
      for (int r = 0; r < 4; ++r)
        Cp[(size_t)(tb + m*16 + r)*D + cb + n*16] = acc[m][n][r];
}

// la = ln(sum of valid partials) : grid H*T. Row t needs kc <= (t>>7)/2.
__global__ __launch_bounds__(256) void k_ln_a(const float* __restrict__ part,
                                              u16* __restrict__ la) {
  __shared__ float sb[8];
  const int row = blockIdx.x;            // h*T + t
  const int h = row >> 10, t = row & 1023;
  const int d = threadIdx.x;
  const int nkc = ((t >> 7) >> 1) + 1;   // valid K-chunks for this row block
  float s = 0.f;
  for (int kc = 0; kc < nkc; ++kc)
    s += part[((size_t)(h*4 + kc)*T + t)*D + d];
  float2 ss = block_sum2(s, s*s, sb);
  const float m = ss.x*(1.f/256.f), var = ss.y*(1.f/256.f) - m*m;
  la[(size_t)row*D + d] = f2bf((s - m) * rsqrtf(var + 1e-5f));
}

// y = relu(la @ decoder_y) * x : grid (64, 8, H) = 2048 blocks (round-10
// proven form). 32KB sb core + half-tile MODE-2 epilogue; ~5 blocks/CU.
__global__ __launch_bounds__(256) void k_gemm_y(const u16* __restrict__ la,
                                                const u16* __restrict__ dyT,
                                                const u16* __restrict__ x,
                                                u16* __restrict__ y) {
  __shared__ char smem[32768];
  const int nt = blockIdx.x, mt = blockIdx.y, h = blockIdx.z;
  f32x4 acc[4][4];
  gemm_bt_core_sb(la + ((size_t)h*T + (size_t)mt*128)*D, D,
                  dyT + ((size_t)h*NH + (size_t)nt*128)*D, D, 4, smem, acc);
  const size_t off = (size_t)mt*128*NF + (size_t)h*NH + (size_t)nt*128;
  store_tile_sb<2>(acc, y + off, NF, x + off, smem);
}

// enc partial = y @ encoder (split-K 32, K=1024/block, nkt=16). Round-16:
// n2 core (48KB, proven r15) with 64-wide encT tiles -> grid 1024 @ 3/CU
// (was 512 @ 2/CU). y A-panels staged 4x instead of 2x but each XCD's 4-kcc
// y slice (~8MB) is L2-resident under the affine decode.
// XCD-affine: each XCD owns 4 kcc slices.
__global__ __launch_bounds__(256) void k_gemm_enc(const u16* __restrict__ y,
                                                  const u16* __restrict__ encT,
                                                  float* __restrict__ part) {
  __shared__ char smem[49152];
  const int slot = blockIdx.x & 7;
  const int seq  = blockIdx.x >> 3;          // 0..127
  const int kcc = slot*4 + (seq >> 5);       // 0..31, K-chunk of 1024
  const int nt = seq & 3;                    // 0..3: 64-col quarter of D
  const int mt = (seq >> 2) & 7;
  f32x4 acc[4][2];
  gemm_bt_core_n2(y + (size_t)mt*128*NF + (size_t)kcc*1024, NF,
                  encT + (size_t)nt*64*NF + (size_t)kcc*1024, NF, 16, smem, acc);
  const int lane = threadIdx.x & 63, wave = threadIdx.x >> 6;
  const int wm = wave >> 1, wn = wave & 1, lr = lane & 15, lk = lane >> 4;
  const int r0 = wm*64 + lk*4, c0 = wn*32 + lr;
  float* Cp = part + (size_t)kcc * T * D;
  const int tb = mt*128 + r0, cb = nt*64 + c0;
  #pragma unroll
  for (int m = 0; m < 4; ++m)
    #pragma unroll
    for (int n = 0; n < 2; ++n)
      #pragma unroll
      for (int r = 0; r < 4; ++r)
        Cp[(size_t)(tb + m*16 + r)*D + cb + n*16] = acc[m][n][r];
}

// v = ln(v + ln(sum of 32 partials)) : grid T
__global__ __launch_bounds__(256) void k_newv(const float* __restrict__ part,
                                              float* __restrict__ v,
                                              u16* __restrict__ vbf, u16* __restrict__ vT) {
  __shared__ float sb[8];
  const int t = blockIdx.x, d = threadIdx.x;
  float s = 0.f;
  #pragma unroll
  for (int kc = 0; kc < 32; ++kc)
    s += part[((size_t)kc*T + t)*D + d];
  float2 ss = block_sum2(s, s*s, sb);
  float m = ss.x*(1.f/256.f), var = ss.y*(1.f/256.f) - m*m;
  const float l1 = (s - m) * rsqrtf(var + 1e-5f);
  const float u = v[(size_t)t*D + d] + l1;
  float2 s2 = block_sum2(u, u*u, sb);
  m = s2.x*(1.f/256.f); var = s2.y*(1.f/256.f) - m*m;
  const float vn = (u - m) * rsqrtf(var + 1e-5f);
  v[(size_t)t*D + d] = vn;
  const u16 bb = f2bf(vn);
  vbf[(size_t)t*D + d] = bb;
  vT[(size_t)d*T + t] = bb;
}

// out = v @ readout (f32 out) : grid (2, 8)
__global__ __launch_bounds__(256) void k_gemm_out(const u16* __restrict__ vbf,
                                                  const u16* __restrict__ roT,
                                                  float* __restrict__ out) {
  __shared__ char smem[65536];
  const int nt = blockIdx.x, mt = blockIdx.y;
  f32x4 acc[4][4];
  gemm_bt_core(vbf + (size_t)mt*128*D, D, roT + (size_t)nt*128*D, D, 4, smem, acc);
  EPILOG_IDX();
  const int tb = mt*128 + r0, cb = nt*128 + c0;
  #pragma unroll
  for (int m = 0; m < 4; ++m)
    #pragma unroll
    for (int n = 0; n < 4; ++n)
      #pragma unroll
      for (int r = 0; r < 4; ++r)
        out[(size_t)(tb + m*16 + r)*D + cb + n*16] = acc[m][n][r];
}

extern "C" void kernel_launch(void* const* d_in, const int* in_sizes, int n_in,
                              void* d_out, int out_size, void* d_ws, size_t ws_size,
                              hipStream_t stream) {
  (void)in_sizes; (void)n_in; (void)out_size; (void)ws_size;  // requires ws_size >= ~252MB
  const int*   idx = (const int*)d_in[0];
  const float* wte = (const float*)d_in[1];
  const float* enc = (const float*)d_in[2];
  const float* dx  = (const float*)d_in[3];
  const float* dy  = (const float*)d_in[4];
  const float* ro  = (const float*)d_in[5];
  float* out = (float*)d_out;
  char* ws = (char*)d_ws;

  u16* dxT  = (u16*)(ws + OFF_DXT);
  u16* dyT  = (u16*)(ws + OFF_DYT);
  u16* encT = (u16*)(ws + OFF_ENCT);
  u16* roT  = (u16*)(ws + OFF_ROT);
  float* cosT = (float*)(ws + OFF_COS);
  float* sinT = (float*)(ws + OFF_SIN);
  float* v    = (float*)(ws + OFF_V);
  u16* vbf  = (u16*)(ws + OFF_VBF);
  u16* vT   = (u16*)(ws + OFF_VT);
  u16* x    = (u16*)(ws + OFF_X);
  u16* xr   = (u16*)(ws + OFF_XR);   // reused as y after scores are done
  u16* sc   = (u16*)(ws + OFF_SC);
  u16* la   = (u16*)(ws + OFF_LA);
  u16* scb  = (u16*)(ws + OFF_PART);         // 32MB bf16 score partials (16 slices)
  float* part = (float*)(ws + OFF_PART);     // 16MB f32 overlay (disjoint in time)

  // weight transposes to bf16 (+rope-pair permutation) + rope tables + initial v
  k_transpose_cvt<1><<<dim3(NH/32, D/32, H), 256, 0, stream>>>(dx, dxT, D, NH);
  k_transpose_cvt<1><<<dim3(NH/32, D/32, H), 256, 0, stream>>>(dy, dyT, D, NH);
  k_transpose_cvt<2><<<dim3(D/32, NF/32, 1), 256, 0, stream>>>(enc, encT, NF, D);
  k_transpose_cvt<0><<<dim3(D/32, D/32, 1), 256, 0, stream>>>(ro, roT, D, D);
  k_rope_table<<<dim3(HALF/256, T), 256, 0, stream>>>(cosT, sinT);
  k_embed<<<T, 256, 0, stream>>>(idx, wte, v, vbf, vT);

  for (int l = 0; l < 6; ++l) {
    k_gemm_x_rope<<<2048,          256, 0, stream>>>(vbf, dxT, x, xr, cosT, sinT);
    k_gemm_sc <<<1152,             256, 0, stream>>>(xr, scb);
    k_sc_combine<<<H*T,            256, 0, stream>>>(scb, sc);
    k_gemm_av <<<320,              256, 0, stream>>>(sc, vT, part);
    k_ln_a    <<<H*T,              256, 0, stream>>>(part, la);
    k_gemm_y  <<<dim3(64, 8, H),   256, 0, stream>>>(la, dyT, x, xr /*as y*/);
    k_gemm_enc<<<1024,             256, 0, stream>>>(xr /*y*/, encT, part);
    k_newv    <<<T,                256, 0, stream>>>(part, v, vbf, vT);
  }
  k_gemm_out<<<dim3(2, 8), 256, 0, stream>>>(vbf, roT, out);
}

// Round 17
// 1197.502 us; speedup vs baseline: 1.0221x; 1.0221x over previous
//
#include <hip/hip_runtime.h>
#include <hip/hip_bf16.h>
#include <stdint.h>

typedef unsigned short u16;
typedef unsigned int u32;
typedef __attribute__((ext_vector_type(8))) short i16x8;   // 8 bf16 payload
typedef __attribute__((ext_vector_type(4))) float f32x4;

#define DEV __device__ __forceinline__

constexpr int T = 1024, D = 256, H = 4, NH = 8192, NF = 32768, HALF = 4096;

// ---------------- workspace layout (bytes); total ~252 MB ----------------
constexpr size_t OFF_DXT  = 0;                                  // (H,NH,D) bf16 [P-perm rows]
constexpr size_t OFF_DYT  = OFF_DXT  + (size_t)H*NH*D*2;        // (H,NH,D) bf16 [P-perm rows]
constexpr size_t OFF_ENCT = OFF_DYT  + (size_t)H*NH*D*2;        // (D,NF)   bf16 [P-perm cols]
constexpr size_t OFF_ROT  = OFF_ENCT + (size_t)D*NF*2;          // (D,D)    bf16
constexpr size_t OFF_COS  = OFF_ROT  + (size_t)D*D*2;           // (T,HALF) f32
constexpr size_t OFF_SIN  = OFF_COS  + (size_t)T*HALF*4;        // (T,HALF) f32
constexpr size_t OFF_V    = OFF_SIN  + (size_t)T*HALF*4;        // (T,D)    f32
constexpr size_t OFF_VBF  = OFF_V    + (size_t)T*D*4;           // (T,D)    bf16
constexpr size_t OFF_VT   = OFF_VBF  + (size_t)T*D*2;           // (D,T)    bf16
constexpr size_t OFF_X    = OFF_VT   + (size_t)T*D*2;           // (T,NF)   bf16 [perm]
constexpr size_t OFF_XR   = OFF_X    + (size_t)T*NF*2;          // (T,NF)   bf16 [perm] (reused as y)
constexpr size_t OFF_SC   = OFF_XR   + (size_t)T*NF*2;          // (H,T,T)  bf16
constexpr size_t OFF_LA   = OFF_SC   + (size_t)H*T*T*2;         // (H,T,D)  bf16
constexpr size_t OFF_PART = OFF_LA   + (size_t)H*T*D*2;         // 32MB: scb (16,T,T) bf16 overlays part (16,T,D) f32
constexpr size_t WS_NEED  = OFF_PART + (size_t)8*T*T*4;

// Feature permutation (within each head's 8192 cols): orig j<4096 -> 2j,
// orig j>=4096 -> 2(j-4096)+1. Pairs (j, j+4096) land adjacent -> rope is local
// to any 16B fragment. Applied to dxT/dyT (out rows) + encT (in rows) at
// prepass; sc/enc are feature-inner-products and y*x is elementwise, so all
// downstream math is permutation-invariant.

DEV u16 f2bf(float f) {            // round-to-nearest-even f32 -> bf16
  u32 u = __float_as_uint(f);
  u += 0x7FFFu + ((u >> 16) & 1u);
  return (u16)(u >> 16);
}
DEV float bf2f(u16 u) { return __uint_as_float(((u32)u) << 16); }

DEV float2 block_sum2(float a, float b, float* sb) {   // 256-thread block, 4 waves
  #pragma unroll
  for (int o = 32; o > 0; o >>= 1) {
    a += __shfl_down(a, o, 64);
    b += __shfl_down(b, o, 64);
  }
  const int w = threadIdx.x >> 6;
  __syncthreads();
  if ((threadIdx.x & 63) == 0) { sb[w*2] = a; sb[w*2+1] = b; }
  __syncthreads();
  return make_float2(sb[0]+sb[2]+sb[4]+sb[6], sb[1]+sb[3]+sb[5]+sb[7]);
}

// ======== 128x128-tile gemm_bt core: C = A(128xK) * B(128xK)^T, bf16->f32 ========
// LDS tile: 128 rows x 64 bf16 (128B/row). XOR swizzle: phys_byte = row*128 +
// (logical_byte ^ ((row&7)<<4)). global_load_lds writes linearly -> pre-swizzle the
// GLOBAL source segment, swizzle again on ds_read (guide rule 21 / T2).
DEV void stage128(const u16* __restrict__ g, int ld, char* lds, int wave, int lane) {
  #pragma unroll
  for (int i = 0; i < 4; ++i) {
    const int f = (wave*4 + i)*64 + lane;       // 0..1023 16B-chunks
    const int row = f >> 3, seg = f & 7;
    const int segl = seg ^ (row & 7);
    const u16* src = g + (size_t)row*ld + segl*8;
    __builtin_amdgcn_global_load_lds(
        (const __attribute__((address_space(1))) void*)src,
        (__attribute__((address_space(3))) void*)(lds + ((wave*4 + i) << 10)),
        16, 0, 0);
  }
}

// 64-row variant (8KB): same 128B-row proven swizzle, 512 chunks, 2/thread
DEV void stageB64(const u16* __restrict__ g, int ld, char* lds, int tid) {
  #pragma unroll
  for (int i = 0; i < 2; ++i) {
    const int f = i*256 + tid;                  // 0..511 16B-chunks
    const int row = f >> 3, seg = f & 7;
    const int segl = seg ^ (row & 7);
    const u16* src = g + (size_t)row*ld + segl*8;
    __builtin_amdgcn_global_load_lds(
        (const __attribute__((address_space(1))) void*)src,
        (__attribute__((address_space(3))) void*)(lds + ((size_t)f << 4)),
        16, 0, 0);
  }
}

// MFMA body for one staged K-tile pair (BK=64 cores)
DEV void mfma_tile(const char* Ac, const char* Bc, int wm, int wn, int lr, int lk,
                   f32x4 acc[4][4]) {
  #pragma unroll
  for (int kk = 0; kk < 2; ++kk) {
    const int lcol = kk*64 + lk*16;
    i16x8 af[4], bfv[4];
    #pragma unroll
    for (int m = 0; m < 4; ++m) {
      const int row = wm*64 + m*16 + lr;
      af[m] = *(const i16x8*)(Ac + row*128 + (lcol ^ ((row & 7) << 4)));
    }
    #pragma unroll
    for (int n = 0; n < 4; ++n) {
      const int row = wn*64 + n*16 + lr;
      bfv[n] = *(const i16x8*)(Bc + row*128 + (lcol ^ ((row & 7) << 4)));
    }
    #pragma unroll
    for (int m = 0; m < 4; ++m)
      #pragma unroll
      for (int n = 0; n < 4; ++n)
        acc[m][n] = __builtin_amdgcn_mfma_f32_16x16x32_bf16(af[m], bfv[n], acc[m][n], 0, 0, 0);
  }
}

// 128x64 output variant: B tile 64 rows, acc[4][2]; same swizzle, BK=64
DEV void mfma_tile_n2(const char* Ac, const char* Bc, int wm, int wn, int lr, int lk,
                      f32x4 acc[4][2]) {
  #pragma unroll
  for (int kk = 0; kk < 2; ++kk) {
    const int lcol = kk*64 + lk*16;
    i16x8 af[4], bfv[2];
    #pragma unroll
    for (int m = 0; m < 4; ++m) {
      const int row = wm*64 + m*16 + lr;
      af[m] = *(const i16x8*)(Ac + row*128 + (lcol ^ ((row & 7) << 4)));
    }
    #pragma unroll
    for (int n = 0; n < 2; ++n) {
      const int row = wn*32 + n*16 + lr;        // 0..63
      bfv[n] = *(const i16x8*)(Bc + row*128 + (lcol ^ ((row & 7) << 4)));
    }
    #pragma unroll
    for (int m = 0; m < 4; ++m)
      #pragma unroll
      for (int n = 0; n < 2; ++n)
        acc[m][n] = __builtin_amdgcn_mfma_f32_16x16x32_bf16(af[m], bfv[n], acc[m][n], 0, 0, 0);
  }
}

// Double-buffered core (64KB LDS): for grid-limited kernels (av, enc, out).
// sb-core rule (round-9): ONLY sb when grid >> 2x CU count.
// Round-11/13 lesson: keep nkt >= 4 and 128B LDS rows (the proven swizzle).
// Round-16 lesson: n2 re-grain ONLY when it partitions output flops (sc);
// halving B while keeping full K doubles staged A-bytes -> regression (enc/av).
DEV void gemm_bt_core(const u16* __restrict__ Ab, int lda,
                      const u16* __restrict__ Bb, int ldb,
                      int nkt, char* smem, f32x4 acc[4][4]) {
  const int tid = threadIdx.x, lane = tid & 63, wave = tid >> 6;
  const int wm = wave >> 1, wn = wave & 1;
  const int lr = lane & 15, lk = lane >> 4;
  char* As = smem;              // 2 x 16KB
  char* Bs = smem + 32768;      // 2 x 16KB
  #pragma unroll
  for (int m = 0; m < 4; ++m)
    #pragma unroll
    for (int n = 0; n < 4; ++n) acc[m][n] = f32x4{0.f, 0.f, 0.f, 0.f};
  stage128(Ab, lda, As, wave, lane);
  stage128(Bb, ldb, Bs, wave, lane);
  __syncthreads();
  for (int kt = 0; kt < nkt; ++kt) {
    const int cur = kt & 1;
    if (kt + 1 < nkt) {           // prefetch next K-tile into other buffer
      stage128(Ab + (size_t)(kt+1)*64, lda, As + ((cur^1) << 14), wave, lane);
      stage128(Bb + (size_t)(kt+1)*64, ldb, Bs + ((cur^1) << 14), wave, lane);
    }
    mfma_tile(As + (cur << 14), Bs + (cur << 14), wm, wn, lr, lk, acc);
    __syncthreads();              // drains vmcnt(0): staged tile visible next iter
  }
}

// 48KB db core: A 128xK (2x16KB), B 64xK (2x8KB) -> 3 blocks/CU.
// Round-15-PROVEN on sc (62.5->56.8us): the N-halving there SPLITS the output
// work across blocks (flop-conserving) — that is the only valid use.
DEV void gemm_bt_core_n2(const u16* __restrict__ Ab, int lda,
                         const u16* __restrict__ Bb, int ldb,
                         int nkt, char* smem, f32x4 acc[4][2]) {
  const int tid = threadIdx.x, lane = tid & 63, wave = tid >> 6;
  const int wm = wave >> 1, wn = wave & 1;
  const int lr = lane & 15, lk = lane >> 4;
  char* As = smem;              // 2 x 16KB
  char* Bs = smem + 32768;      // 2 x 8KB
  #pragma unroll
  for (int m = 0; m < 4; ++m)
    #pragma unroll
    for (int n = 0; n < 2; ++n) acc[m][n] = f32x4{0.f, 0.f, 0.f, 0.f};
  stage128(Ab, lda, As, wave, lane);
  stageB64(Bb, ldb, Bs, tid);
  __syncthreads();
  for (int kt = 0; kt < nkt; ++kt) {
    const int cur = kt & 1;
    if (kt + 1 < nkt) {
      stage128(Ab + (size_t)(kt+1)*64, lda, As + ((cur^1) << 14), wave, lane);
      stageB64(Bb + (size_t)(kt+1)*64, ldb, Bs + ((cur^1) << 13), tid);
    }
    mfma_tile_n2(As + (cur << 14), Bs + (cur << 13), wm, wn, lr, lk, acc);
    __syncthreads();
  }
}

// Single-buffered core (32KB LDS): ONLY for huge-grid kernels (x_rope: 2048
// blocks, y: 2048 blocks). Stage latency exposed per iteration, but ~5
// blocks/CU of cross-block TLP covers it (verified round 8: x_rope 72->61us).
// NO min-waves launch bound (round-7: (256,5) capped VGPR at 48 -> spills).
DEV void gemm_bt_core_sb(const u16* __restrict__ Ab, int lda,
                         const u16* __restrict__ Bb, int ldb,
                         int nkt, char* smem, f32x4 acc[4][4]) {
  const int tid = threadIdx.x, lane = tid & 63, wave = tid >> 6;
  const int wm = wave >> 1, wn = wave & 1;
  const int lr = lane & 15, lk = lane >> 4;
  char* As = smem;              // 16KB
  char* Bs = smem + 16384;      // 16KB
  #pragma unroll
  for (int m = 0; m < 4; ++m)
    #pragma unroll
    for (int n = 0; n < 4; ++n) acc[m][n] = f32x4{0.f, 0.f, 0.f, 0.f};
  for (int kt = 0; kt < nkt; ++kt) {
    stage128(Ab + (size_t)kt*64, lda, As, wave, lane);
    stage128(Bb + (size_t)kt*64, ldb, Bs, wave, lane);
    __syncthreads();
    mfma_tile(As, Bs, wm, wn, lr, lk, acc);
    __syncthreads();
  }
}

// C/D frag map (m89-verified): col = lane&15, row = (lane>>4)*4 + reg
#define EPILOG_IDX() \
  const int lane = threadIdx.x & 63, wave = threadIdx.x >> 6; \
  const int wm = wave >> 1, wn = wave & 1, lr = lane & 15, lk = lane >> 4; \
  const int r0 = wm*64 + lk*4; \
  const int c0 = wn*64 + lr;

constexpr int TS = 136;   // LDS row stride (u16): 272B, 16B-aligned, bank-spread

// ---- 128x64 coalesced store via LDS [128][72] (18.4KB, fits 48KB smem) ----
// (numerically verified in rounds 11/15)
DEV void store_tile64(const f32x4 acc[4][2], u16* __restrict__ dst, int ld, char* smem) {
  u16* tb = (u16*)smem;
  const int lane = threadIdx.x & 63, wave = threadIdx.x >> 6;
  const int wm = wave >> 1, wn = wave & 1, lr = lane & 15, lk = lane >> 4;
  const int r0 = wm*64 + lk*4, c0 = wn*32 + lr;
  #pragma unroll
  for (int m = 0; m < 4; ++m)
    #pragma unroll
    for (int n = 0; n < 2; ++n)
      #pragma unroll
      for (int r = 0; r < 4; ++r)
        tb[(size_t)(r0 + m*16 + r)*72 + c0 + n*16] = f2bf(acc[m][n][r]);
  __syncthreads();
  const int rr = threadIdx.x >> 3;         // 0..31
  const int cc = (threadIdx.x & 7)*8;      // 0..56 (u16 units)
  #pragma unroll
  for (int it = 0; it < 4; ++it) {
    const int row = it*32 + rr;
    *(i16x8*)(dst + (size_t)row*ld + cc) = *(const i16x8*)(tb + (size_t)row*72 + cc);
  }
}

// ---- half-tile coalesced store (64 rows/pass, 17.4KB LDS; fits 32KB smem) ----
// Rows 0-63 live in waves 0-1 (wm=0), rows 64-127 in waves 2-3 (wm=1).
template<int MODE>
DEV void store_tile_sb(const f32x4 acc[4][4], u16* __restrict__ dst, int ld,
                       const u16* __restrict__ xg, char* smem) {
  u16* tb = (u16*)smem;                    // 64 x TS u16 = 17.4KB
  const int lane = threadIdx.x & 63, wave = threadIdx.x >> 6;
  const int wm = wave >> 1, wn = wave & 1, lr = lane & 15, lk = lane >> 4;
  const int c0 = wn*64 + lr, rb = lk*4;
  const int rr = threadIdx.x >> 4, cc = (threadIdx.x & 15)*8;
  #pragma unroll
  for (int half = 0; half < 2; ++half) {
    if (wm == half) {
      #pragma unroll
      for (int m = 0; m < 4; ++m)
        #pragma unroll
        for (int n = 0; n < 4; ++n)
          #pragma unroll
          for (int r = 0; r < 4; ++r) {
            float v = acc[m][n][r];
            if (MODE >= 1) v = fmaxf(v, 0.f);
            tb[(size_t)(rb + m*16 + r)*TS + c0 + n*16] = f2bf(v);
          }
    }
    __syncthreads();
    #pragma unroll
    for (int it = 0; it < 4; ++it) {
      const int row = it*16 + rr;            // 0..63
      const int grow = half*64 + row;
      i16x8 w = *(const i16x8*)(tb + (size_t)row*TS + cc);
      if (MODE == 2) {
        const i16x8 xv = *(const i16x8*)(xg + (size_t)grow*ld + cc);
        #pragma unroll
        for (int j = 0; j < 8; ++j)
          w[j] = (short)f2bf(bf2f((u16)w[j]) * bf2f((u16)xv[j]));
      }
      *(i16x8*)(dst + (size_t)grow*ld + cc) = w;
    }
    __syncthreads();
  }
}

// ---------------- pre-pass kernels ----------------
// PERM 0: plain transpose+cvt.
// PERM 1: apply rope-pair perm to OUTPUT row index (within-head 8192): dxT/dyT.
// PERM 2: apply inverse perm to INPUT row index (global NF, per-head): encT.
template<int PERM>
__global__ __launch_bounds__(256) void k_transpose_cvt(const float* __restrict__ in,
                                                       u16* __restrict__ out, int R, int C) {
  __shared__ float tile[32][33];
  const size_t zoff = (size_t)blockIdx.z * R * C;
  const float* inz = in + zoff;
  u16* outz = out + zoff;
  const int c0 = blockIdx.x << 5, rr0 = blockIdx.y << 5;
  const int tx = threadIdx.x & 31, ty = threadIdx.x >> 5;
  #pragma unroll
  for (int i = 0; i < 4; ++i) {
    int irow = rr0 + ty + i*8;
    if (PERM == 2) {               // new col f holds orig feature Pinv(f)
      const int hh = irow >> 13, j = irow & 8191;
      irow = hh*8192 + ((j & 1) ? (j >> 1) + 4096 : (j >> 1));
    }
    tile[ty + i*8][tx] = inz[(size_t)irow*C + c0 + tx];
  }
  __syncthreads();
  #pragma unroll
  for (int i = 0; i < 4; ++i) {
    const int rr = ty + i*8;
    int orow = c0 + rr;
    if (PERM == 1) {               // orig feature j lands at slot P(j)
      const int j = orow & 8191;
      orow = (orow & ~8191) | ((j < 4096) ? 2*j : 2*(j - 4096) + 1);
    }
    outz[(size_t)orow*R + rr0 + tx] = f2bf(tile[tx][rr]);
  }
}

// tables in (T, HALF) layout: cosT[t*HALF + p], p = pair index
__global__ __launch_bounds__(256) void k_rope_table(float* __restrict__ cosT,
                                                    float* __restrict__ sinT) {
  const int i = blockIdx.x*256 + threadIdx.x;    // 0..4095
  const int t = blockIdx.y;
  const float p = (float)i * (1.f/4096.f);
  const float ang = (float)t * expf(-9.210340371976184f * p);  // 10000^(-i/half)
  cosT[(size_t)t*HALF + i] = cosf(ang);
  sinT[(size_t)t*HALF + i] = sinf(ang);
}

__global__ __launch_bounds__(256) void k_embed(const int* __restrict__ idx,
                                               const float* __restrict__ wte,
                                               float* __restrict__ v,
                                               u16* __restrict__ vbf, u16* __restrict__ vT) {
  __shared__ float sb[8];
  const int t = blockIdx.x, d = threadIdx.x;
  const float val = wte[(size_t)idx[t]*D + d];
  float2 ss = block_sum2(val, val*val, sb);
  const float m = ss.x*(1.f/256.f), var = ss.y*(1.f/256.f) - m*m;
  const float vn = (val - m) * rsqrtf(var + 1e-5f);
  v[(size_t)t*D + d] = vn;
  const u16 b = f2bf(vn);
  vbf[(size_t)t*D + d] = b;
  vT[(size_t)d*T + t] = b;
}

// ---------------- per-layer kernels ----------------
// x = relu(v @ decoder_x) AND xr = rope(x), fused via the pair permutation.
// 1-D grid 2048, XCD-affine decode: the rope-table slice for (nt,mt) is
// h-INDEPENDENT, so the 4 h-variants are placed on the SAME XCD (p%8) within
// 32 dispatch slots -> table fetched once per XCD, not 4x. Per-XCD unique set
// ~ 4MB tables + 2MB dxT + 0.5MB vbf: L2-resident. (round 9: ~-8us/dispatch)
__global__ __launch_bounds__(256) void k_gemm_x_rope(const u16* __restrict__ vbf,
                                                     const u16* __restrict__ dxT,
                                                     u16* __restrict__ x,
                                                     u16* __restrict__ xr,
                                                     const float* __restrict__ cosT,
                                                     const float* __restrict__ sinT) {
  __shared__ char smem[32768];
  const int p = blockIdx.x;
  const int slot = p & 7;
  const int h = (p >> 3) & 3;
  const int seq = p >> 5;                   // 0..63
  const int nt = slot*8 + (seq & 7);        // 0..63
  const int mt = seq >> 3;                  // 0..7
  f32x4 acc[4][4];
  gemm_bt_core_sb(vbf + (size_t)mt*128*D, D,
                  dxT + ((size_t)h*NH + (size_t)nt*128)*D, D, 4, smem, acc);
  u16* tb = (u16*)smem;
  const int lane = threadIdx.x & 63, wave = threadIdx.x >> 6;
  const int wm = wave >> 1, wn = wave & 1, lr = lane & 15, lk = lane >> 4;
  const int c0 = wn*64 + lr, rb = lk*4;
  const int rr = threadIdx.x >> 4, cc = (threadIdx.x & 15)*8;
  const size_t obase = (size_t)mt*128*NF + (size_t)h*NH + (size_t)nt*128;
  const int pbase = (nt*128 + cc) >> 1;    // pair index in [0,4096), mult of 4
  #pragma unroll
  for (int half = 0; half < 2; ++half) {
    if (wm == half) {
      #pragma unroll
      for (int m = 0; m < 4; ++m)
        #pragma unroll
        for (int n = 0; n < 4; ++n)
          #pragma unroll
          for (int r = 0; r < 4; ++r)
            tb[(size_t)(rb + m*16 + r)*TS + c0 + n*16] = f2bf(fmaxf(acc[m][n][r], 0.f));
    }
    __syncthreads();
    #pragma unroll
    for (int it = 0; it < 4; ++it) {
      const int row = it*16 + rr;            // 0..63
      const int grow = half*64 + row;
      const i16x8 w = *(const i16x8*)(tb + (size_t)row*TS + cc);
      *(i16x8*)(x + obase + (size_t)grow*NF + cc) = w;
      const int t = mt*128 + grow;
      const float4 cv = *(const float4*)(cosT + (size_t)t*HALF + pbase);
      const float4 sv = *(const float4*)(sinT + (size_t)t*HALF + pbase);
      i16x8 rg;
      float x1, x2;
      x1 = bf2f((u16)w[0]); x2 = bf2f((u16)w[1]);
      rg[0] = (short)f2bf(x1*cv.x - x2*sv.x); rg[1] = (short)f2bf(x2*cv.x + x1*sv.x);
      x1 = bf2f((u16)w[2]); x2 = bf2f((u16)w[3]);
      rg[2] = (short)f2bf(x1*cv.y - x2*sv.y); rg[3] = (short)f2bf(x2*cv.y + x1*sv.y);
      x1 = bf2f((u16)w[4]); x2 = bf2f((u16)w[5]);
      rg[4] = (short)f2bf(x1*cv.z - x2*sv.z); rg[5] = (short)f2bf(x2*cv.z + x1*sv.z);
      x1 = bf2f((u16)w[6]); x2 = bf2f((u16)w[7]);
      rg[6] = (short)f2bf(x1*cv.w - x2*sv.w); rg[7] = (short)f2bf(x2*cv.w + x1*sv.w);
      *(i16x8*)(xr + obase + (size_t)grow*NF + cc) = rg;
    }
    __syncthreads();
  }
}

// scores partial = xr_h @ xr_h^T over K-chunk (split-K 4 -> K=2048/block),
// LOWER-TRIANGLE TILES ONLY. Round-15 proven: 128x64 tiles via 48KB n2 core
// (BK=64, nkt=32) -> 3 blocks/CU; 56.8us, occupancy 22%, conflicts flat.
// Grid 1152 = 36 tiles x 2 N-halves x 16 slices (flop-conserving split).
// XCD-affine: slice = p&15 -> XCD p%8 serves slices {z, z+8}.
__global__ __launch_bounds__(256) void k_gemm_sc(const u16* __restrict__ xr,
                                                 u16* __restrict__ scb) {
  __shared__ char smem[49152];
  const int z = blockIdx.x & 15;            // slice = h*4 + kc
  const int j = blockIdx.x >> 4;            // 0..71
  const int i = j >> 1;                     // 0..35 lower-triangle tile id
  const int nh = j & 1;                     // N-half of the 128x128 tile
  int tt = 0;
  while ((tt + 1)*(tt + 2)/2 <= i) ++tt;
  const int st = i - tt*(tt + 1)/2;         // st <= tt (strict-mask survivors)
  const int h = z >> 2, kc = z & 3;
  const u16* base = xr + (size_t)h*NH + (size_t)kc*2048;
  f32x4 acc[4][2];
  gemm_bt_core_n2(base + (size_t)tt*128*NF, NF,
                  base + ((size_t)st*128 + (size_t)nh*64)*NF, NF, 32, smem, acc);
  store_tile64(acc, scb + (size_t)z*T*T + (size_t)tt*128*T + (size_t)st*128 + (size_t)nh*64,
               T, smem);
}

// combine 4 K-chunks + strict-causal mask -> bf16 scores : grid H*T
__global__ __launch_bounds__(256) void k_sc_combine(const u16* __restrict__ scb,
                                                    u16* __restrict__ sc) {
  const int row = blockIdx.x;               // h*T + t
  const int h = row >> 10, t = row & 1023;
  const u16* p0 = scb + ((size_t)(h*4 + 0)*T + t)*T;
  u16* o = sc + (size_t)row*T;
  const int s0 = threadIdx.x*4;
  ushort4 r;
  if (s0 >= t) {
    r.x = 0; r.y = 0; r.z = 0; r.w = 0;
  } else {
    const ushort4 a0 = *(const ushort4*)(p0 + s0);
    const ushort4 a1 = *(const ushort4*)(p0 + T*T + s0);
    const ushort4 a2 = *(const ushort4*)(p0 + 2*(size_t)T*T + s0);
    const ushort4 a3 = *(const ushort4*)(p0 + 3*(size_t)T*T + s0);
    const float vx = bf2f(a0.x) + bf2f(a1.x) + bf2f(a2.x) + bf2f(a3.x);
    const float vy = bf2f(a0.y) + bf2f(a1.y) + bf2f(a2.y) + bf2f(a3.y);
    const float vz = bf2f(a0.z) + bf2f(a1.z) + bf2f(a2.z) + bf2f(a3.z);
    const float vw = bf2f(a0.w) + bf2f(a1.w) + bf2f(a2.w) + bf2f(a3.w);
    r.x = f2bf((s0 + 0 < t) ? vx : 0.f);
    r.y = f2bf((s0 + 1 < t) ? vy : 0.f);
    r.z = f2bf((s0 + 2 < t) ? vz : 0.f);
    r.w = f2bf((s0 + 3 < t) ? vw : 0.f);
  }
  *(ushort4*)(o + s0) = r;
}

// a-partial = scores @ v (split-K 4, K=256/block, nkt=4), VALID (mt,kc) PAIRS
// ONLY: kc <= mt/2 -> 20 of 32 pairs. 1-D grid 160 (round-10/14 proven form;
// round-16's n2 attempt doubled staged A-bytes -> regression).
// XCD-affine: slot = p%8 -> (h,nt).
__global__ __launch_bounds__(256) void k_gemm_av(const u16* __restrict__ sc,
                                                 const u16* __restrict__ vT,
                                                 float* __restrict__ part) {
  __shared__ char smem[65536];
  const int slot = blockIdx.x & 7;
  const int h = slot >> 1, nt = slot & 1;
  int mt = 0, kc = 0, rem = blockIdx.x >> 3;  // 0..19 -> (mt, kc), kc <= mt/2
  #pragma unroll
  for (int m = 0; m < 8; ++m) {
    const int c = (m >> 1) + 1;
    if (rem < c) { mt = m; kc = rem; break; }
    rem -= c;
  }
  f32x4 acc[4][4];
  gemm_bt_core(sc + ((size_t)h*T + (size_t)mt*128)*T + (size_t)kc*256, T,
               vT + (size_t)nt*128*T + (size_t)kc*256, T, 4, smem, acc);
  EPILOG_IDX();
  float* Cp = part + (size_t)(h*4 + kc) * T * D;
  const int tb = mt*128 + r0, cb = nt*128 + c0;
  #pragma unroll
  for (int m = 0; m < 4; ++m)
    #pragma unroll
    for (int n = 0; n < 4; ++n)
      #pragma unroll
      for (int r = 0; r < 4; ++r)
        Cp[(size_t)(tb + m*16 + r)*D + cb + n*16] = acc[m][n][r];
}

// la = ln(sum of valid partials) : grid H*T. Row t needs kc <= (t>>7)/2.
__global__ __launch_bounds__(256) void k_ln_a(const float* __restrict__ part,
                                              u16* __restrict__ la) {
  __shared__ float sb[8];
  const int row = blockIdx.x;            // h*T + t
  const int h = row >> 10, t = row & 1023;
  const int d = threadIdx.x;
  const int nkc = ((t >> 7) >> 1) + 1;   // valid K-chunks for this row block
  float s = 0.f;
  for (int kc = 0; kc < nkc; ++kc)
    s += part[((size_t)(h*4 + kc)*T + t)*D + d];
  float2 ss = block_sum2(s, s*s, sb);
  const float m = ss.x*(1.f/256.f), var = ss.y*(1.f/256.f) - m*m;
  la[(size_t)row*D + d] = f2bf((s - m) * rsqrtf(var + 1e-5f));
}

// y = relu(la @ decoder_y) * x : grid (64, 8, H) = 2048 blocks (round-10
// proven form). 32KB sb core + half-tile MODE-2 epilogue; ~5 blocks/CU.
__global__ __launch_bounds__(256) void k_gemm_y(const u16* __restrict__ la,
                                                const u16* __restrict__ dyT,
                                                const u16* __restrict__ x,
                                                u16* __restrict__ y) {
  __shared__ char smem[32768];
  const int nt = blockIdx.x, mt = blockIdx.y, h = blockIdx.z;
  f32x4 acc[4][4];
  gemm_bt_core_sb(la + ((size_t)h*T + (size_t)mt*128)*D, D,
                  dyT + ((size_t)h*NH + (size_t)nt*128)*D, D, 4, smem, acc);
  const size_t off = (size_t)mt*128*NF + (size_t)h*NH + (size_t)nt*128;
  store_tile_sb<2>(acc, y + off, NF, x + off, smem);
}

// enc partial = y @ encoder (split-K 32, K=1024/block, nkt=16). 1-D grid 512
// (round-14 proven form; round-16's n2 attempt staged y 4x -> regression).
// encT cols permuted to match y -> inner product invariant.
// XCD-affine: each XCD owns 4 kcc slices (~10MB y+encT) -> L2-local.
__global__ __launch_bounds__(256) void k_gemm_enc(const u16* __restrict__ y,
                                                  const u16* __restrict__ encT,
                                                  float* __restrict__ part) {
  __shared__ char smem[65536];
  const int slot = blockIdx.x & 7;
  const int seq  = blockIdx.x >> 3;          // 0..63
  const int kcc = slot*4 + (seq >> 4);       // 0..31, K-chunk of 1024
  const int nt = seq & 1;
  const int mt = (seq >> 1) & 7;
  f32x4 acc[4][4];
  gemm_bt_core(y + (size_t)mt*128*NF + (size_t)kcc*1024, NF,
               encT + (size_t)nt*128*NF + (size_t)kcc*1024, NF, 16, smem, acc);
  EPILOG_IDX();
  float* Cp = part + (size_t)kcc * T * D;
  const int tb = mt*128 + r0, cb = nt*128 + c0;
  #pragma unroll
  for (int m = 0; m < 4; ++m)
    #pragma unroll
    for (int n = 0; n < 4; ++n)
      #pragma unroll
      for (int r = 0; r < 4; ++r)
        Cp[(size_t)(tb + m*16 + r)*D + cb + n*16] = acc[m][n][r];
}

// v = ln(v + ln(sum of 32 partials)) : grid T
__global__ __launch_bounds__(256) void k_newv(const float* __restrict__ part,
                                              float* __restrict__ v,
                                              u16* __restrict__ vbf, u16* __restrict__ vT) {
  __shared__ float sb[8];
  const int t = blockIdx.x, d = threadIdx.x;
  float s = 0.f;
  #pragma unroll
  for (int kc = 0; kc < 32; ++kc)
    s += part[((size_t)kc*T + t)*D + d];
  float2 ss = block_sum2(s, s*s, sb);
  float m = ss.x*(1.f/256.f), var = ss.y*(1.f/256.f) - m*m;
  const float l1 = (s - m) * rsqrtf(var + 1e-5f);
  const float u = v[(size_t)t*D + d] + l1;
  float2 s2 = block_sum2(u, u*u, sb);
  m = s2.x*(1.f/256.f); var = s2.y*(1.f/256.f) - m*m;
  const float vn = (u - m) * rsqrtf(var + 1e-5f);
  v[(size_t)t*D + d] = vn;
  const u16 bb = f2bf(vn);
  vbf[(size_t)t*D + d] = bb;
  vT[(size_t)d*T + t] = bb;
}

// out = v @ readout (f32 out) : grid (2, 8)
__global__ __launch_bounds__(256) void k_gemm_out(const u16* __restrict__ vbf,
                                                  const u16* __restrict__ roT,
                                                  float* __restrict__ out) {
  __shared__ char smem[65536];
  const int nt = blockIdx.x, mt = blockIdx.y;
  f32x4 acc[4][4];
  gemm_bt_core(vbf + (size_t)mt*128*D, D, roT + (size_t)nt*128*D, D, 4, smem, acc);
  EPILOG_IDX();
  const int tb = mt*128 + r0, cb = nt*128 + c0;
  #pragma unroll
  for (int m = 0; m < 4; ++m)
    #pragma unroll
    for (int n = 0; n < 4; ++n)
      #pragma unroll
      for (int r = 0; r < 4; ++r)
        out[(size_t)(tb + m*16 + r)*D + cb + n*16] = acc[m][n][r];
}

extern "C" void kernel_launch(void* const* d_in, const int* in_sizes, int n_in,
                              void* d_out, int out_size, void* d_ws, size_t ws_size,
                              hipStream_t stream) {
  (void)in_sizes; (void)n_in; (void)out_size; (void)ws_size;  // requires ws_size >= ~252MB
  const int*   idx = (const int*)d_in[0];
  const float* wte = (const float*)d_in[1];
  const float* enc = (const float*)d_in[2];
  const float* dx  = (const float*)d_in[3];
  const float* dy  = (const float*)d_in[4];
  const float* ro  = (const float*)d_in[5];
  float* out = (float*)d_out;
  char* ws = (char*)d_ws;

  u16* dxT  = (u16*)(ws + OFF_DXT);
  u16* dyT  = (u16*)(ws + OFF_DYT);
  u16* encT = (u16*)(ws + OFF_ENCT);
  u16* roT  = (u16*)(ws + OFF_ROT);
  float* cosT = (float*)(ws + OFF_COS);
  float* sinT = (float*)(ws + OFF_SIN);
  float* v    = (float*)(ws + OFF_V);
  u16* vbf  = (u16*)(ws + OFF_VBF);
  u16* vT   = (u16*)(ws + OFF_VT);
  u16* x    = (u16*)(ws + OFF_X);
  u16* xr   = (u16*)(ws + OFF_XR);   // reused as y after scores are done
  u16* sc   = (u16*)(ws + OFF_SC);
  u16* la   = (u16*)(ws + OFF_LA);
  u16* scb  = (u16*)(ws + OFF_PART);         // 32MB bf16 score partials (16 slices)
  float* part = (float*)(ws + OFF_PART);     // 16MB f32 overlay (disjoint in time)

  // weight transposes to bf16 (+rope-pair permutation) + rope tables + initial v
  k_transpose_cvt<1><<<dim3(NH/32, D/32, H), 256, 0, stream>>>(dx, dxT, D, NH);
  k_transpose_cvt<1><<<dim3(NH/32, D/32, H), 256, 0, stream>>>(dy, dyT, D, NH);
  k_transpose_cvt<2><<<dim3(D/32, NF/32, 1), 256, 0, stream>>>(enc, encT, NF, D);
  k_transpose_cvt<0><<<dim3(D/32, D/32, 1), 256, 0, stream>>>(ro, roT, D, D);
  k_rope_table<<<dim3(HALF/256, T), 256, 0, stream>>>(cosT, sinT);
  k_embed<<<T, 256, 0, stream>>>(idx, wte, v, vbf, vT);

  for (int l = 0; l < 6; ++l) {
    k_gemm_x_rope<<<2048,          256, 0, stream>>>(vbf, dxT, x, xr, cosT, sinT);
    k_gemm_sc <<<1152,             256, 0, stream>>>(xr, scb);
    k_sc_combine<<<H*T,            256, 0, stream>>>(scb, sc);
    k_gemm_av <<<160,              256, 0, stream>>>(sc, vT, part);
    k_ln_a    <<<H*T,              256, 0, stream>>>(part, la);
    k_gemm_y  <<<dim3(64, 8, H),   256, 0, stream>>>(la, dyT, x, xr /*as y*/);
    k_gemm_enc<<<512,              256, 0, stream>>>(xr /*y*/, encT, part);
    k_newv    <<<T,                256, 0, stream>>>(part, v, vbf, vT);
  }
  k_gemm_out<<<dim3(2, 8), 256, 0, stream>>>(vbf, roT, out);
}